// Round 1
// baseline (325.384 us; speedup 1.0000x reference)
//
#include <hip/hip_runtime.h>
#include <math.h>

#define KCH 32          // channels k
#define Q 64            // taps q
#define LSTEP 240       // new timesteps per block
#define WARM 16         // contraction warm-up steps
#define TT (LSTEP + WARM)   // 256 tile steps
#define TILE_X (TT + Q)     // 320 staged data entries
#define SROW 36             // padded LDS row stride (16B-aligned, breaks conflicts)

__device__ __forceinline__ float sp_softplus(float x) {
    return (x > 15.f) ? x : log1pf(expf(x));
}

// butterfly sum over lanes within each quad (lanes 0..3), via DPP quad_perm
__device__ __forceinline__ float quad_sum4(float v) {
    int vi = __float_as_int(v);
    int p1 = __builtin_amdgcn_update_dpp(0, vi, 0xB1, 0xF, 0xF, true); // xor 1
    v += __int_as_float(p1);
    vi = __float_as_int(v);
    int p2 = __builtin_amdgcn_update_dpp(0, vi, 0x4E, 0xF, 0xF, true); // xor 2
    v += __int_as_float(p2);
    return v;
}

// --- K1: sum(u2), sum(u2^2) ---------------------------------------------
extern "C" __global__ void k1_stats(const float* __restrict__ r,
                                    const float* __restrict__ a0p,
                                    const float* __restrict__ a1p,
                                    float* __restrict__ wsf, int n) {
    const float a0 = a0p[0], a1 = a1p[0];
    float s1 = 0.f, s2 = 0.f;
    for (int t = blockIdx.x * blockDim.x + threadIdx.x; t < n;
         t += gridDim.x * blockDim.x) {
        float u = r[t + 1] - a0 - a1 * r[t];
        float u2 = u * u;
        s1 += u2;
        s2 += u2 * u2;
    }
#pragma unroll
    for (int off = 32; off > 0; off >>= 1) {
        s1 += __shfl_down(s1, off);
        s2 += __shfl_down(s2, off);
    }
    __shared__ float b1[8], b2[8];
    int wid = threadIdx.x >> 6;
    if ((threadIdx.x & 63) == 0) { b1[wid] = s1; b2[wid] = s2; }
    __syncthreads();
    if (threadIdx.x == 0) {
        float t1 = 0.f, t2 = 0.f;
        int nw = blockDim.x >> 6;
        for (int i = 0; i < nw; i++) { t1 += b1[i]; t2 += b2[i]; }
        atomicAdd(&wsf[0], t1);
        atomicAdd(&wsf[1], t2);
    }
}

// --- K2: variance + softplus params into ws ------------------------------
// ws layout (floats): [0]=sum_u2 [1]=sum_u2sq [2]=var [3]=sigma2_init
// [4]=acc_sumlog [5]=acc_sumratio [6]=beta0 [8..40)=beta [40..72)=rho
// [72..104)=w0  [128..128+2048)=PW[m][i]  [2176..4224)=PG[m][i]
extern "C" __global__ void k2_params(float* __restrict__ wsf,
                                     const float* __restrict__ rb0,
                                     const float* __restrict__ rb,
                                     const float* __restrict__ rw0,
                                     const float* __restrict__ rw,
                                     const float* __restrict__ rg,
                                     const float* __restrict__ rr, int n) {
    int tid = threadIdx.x;
    if (tid == 0) {
        float s1 = wsf[0], s2 = wsf[1];
        float nf = (float)n;
        float mean = s1 / nf;
        float var = fmaxf((s2 - nf * mean * mean) / (nf - 1.f), 0.f);
        wsf[2] = var;
        wsf[3] = var + 1e-6f;
        wsf[6] = sp_softplus(rb0[0]);
    }
    if (tid < KCH) {
        wsf[8 + tid]  = sp_softplus(rb[tid]);
        wsf[40 + tid] = sp_softplus(rr[tid]);
        wsf[72 + tid] = sp_softplus(rw0[tid]);
    }
    for (int idx = tid; idx < KCH * Q; idx += blockDim.x) {
        int m = idx >> 5;       // tap index (already reversed)
        int i = idx & 31;       // channel
        wsf[128 + idx]           = sp_softplus(rw[i * Q + (Q - 1 - m)]);
        wsf[128 + KCH * Q + idx] = sp_softplus(rg[i * Q + (Q - 1 - m)]);
    }
}

// --- K3: fused conv + chunked scan + NLL partials ------------------------
extern "C" __global__ void __launch_bounds__(256, 4)
k3_main(const float* __restrict__ r, const float* __restrict__ vol,
        const float* __restrict__ a0p, const float* __restrict__ a1p,
        const float* __restrict__ pw, const float* __restrict__ pg,
        const float* __restrict__ pbeta, const float* __restrict__ prho,
        const float* __restrict__ pw0, const float* __restrict__ pscal,
        float* __restrict__ pacc, int n) {
    __shared__ float Ul[TILE_X];
    __shared__ float Vl[TILE_X];
    __shared__ float Sl[TT + 1][SROW];   // +1 row: safe unconditional prefetch

    const int c = blockIdx.x;
    const int tg0 = (c == 0) ? 0 : c * LSTEP - WARM;
    const int warm = (c == 0) ? 0 : WARM;
    const float a0 = a0p[0], a1 = a1p[0];
    const float var = pscal[2];

    // stage U (u2_full) and V (vol_full) windows for this tile
    for (int idx = threadIdx.x; idx < TILE_X; idx += blockDim.x) {
        int x = tg0 + idx;
        float uval, vval;
        if (x < Q) {
            uval = var;        // init_u2 entries
            vval = vol[0];
        } else {
            int t = x - Q;
            uval = 0.f; vval = 0.f;
            if (t < n) {
                float u = r[t + 1] - a0 - a1 * r[t];
                uval = u * u;
                vval = vol[t];
            }
        }
        Ul[idx] = uval;
        Vl[idx] = vval;
    }
    __syncthreads();

    // ---- conv: each thread computes s[tloc, 0..31] -----------------------
    {
        const int tloc = threadIdx.x;   // 0..255
        float acc[KCH];
#pragma unroll
        for (int i = 0; i < KCH; i++) acc[i] = pw0[i];   // uniform -> s_load
#pragma unroll 4
        for (int m = 0; m < Q; m++) {
            float uv = Ul[tloc + m];
            float vv = Vl[tloc + m];
            const float* __restrict__ wrow = pw + m * KCH;  // wave-uniform addr
            const float* __restrict__ grow = pg + m * KCH;
#pragma unroll
            for (int i = 0; i < KCH; i++)
                acc[i] = fmaf(uv, wrow[i], fmaf(vv, grow[i], acc[i]));
        }
#pragma unroll
        for (int g = 0; g < KCH / 4; g++) {
            float4 v4 = make_float4(acc[4 * g], acc[4 * g + 1],
                                    acc[4 * g + 2], acc[4 * g + 3]);
            *reinterpret_cast<float4*>(&Sl[tloc][4 * g]) = v4;
        }
    }
    __syncthreads();

    // ---- scan: lanes 0..3, 8 channels each, DPP butterfly reduce ---------
    if (threadIdx.x < 4) {
        const int j = threadIdx.x;
        float rho_c[8], beta_c[8];
#pragma unroll
        for (int e = 0; e < 8; e++) {
            rho_c[e]  = prho[j * 8 + e];
            beta_c[e] = pbeta[j * 8 + e];
        }
        const float beta0 = pscal[6];
        float sig = pscal[3];                  // sigma2_init warm start
        const int send = min(warm + LSTEP, n - tg0);
        float sumlog = 0.f, sumratio = 0.f;

        float4 A = *reinterpret_cast<const float4*>(&Sl[0][j * 8]);
        float4 B = *reinterpret_cast<const float4*>(&Sl[0][j * 8 + 4]);
        for (int s2 = 0; s2 < send; s2++) {
            // prefetch next row (row TT is allocated; garbage unused)
            float4 An = *reinterpret_cast<const float4*>(&Sl[s2 + 1][j * 8]);
            float4 Bn = *reinterpret_cast<const float4*>(&Sl[s2 + 1][j * 8 + 4]);
            float h0 = fmaxf(fmaf(rho_c[0], sig, A.x), 0.f) * beta_c[0];
            float h1 = fmaxf(fmaf(rho_c[1], sig, A.y), 0.f) * beta_c[1];
            float h2 = fmaxf(fmaf(rho_c[2], sig, A.z), 0.f) * beta_c[2];
            float h3 = fmaxf(fmaf(rho_c[3], sig, A.w), 0.f) * beta_c[3];
            float h4 = fmaxf(fmaf(rho_c[4], sig, B.x), 0.f) * beta_c[4];
            float h5 = fmaxf(fmaf(rho_c[5], sig, B.y), 0.f) * beta_c[5];
            float h6 = fmaxf(fmaf(rho_c[6], sig, B.z), 0.f) * beta_c[6];
            float h7 = fmaxf(fmaf(rho_c[7], sig, B.w), 0.f) * beta_c[7];
            float d = ((h0 + h1) + (h2 + h3)) + ((h4 + h5) + (h6 + h7));
            d = quad_sum4(d);                  // sum over 4 lanes (32 channels)
            sig = beta0 + d + 1e-8f;
            if (s2 >= warm) {
                sumlog += __logf(sig);
                sumratio += Ul[s2 + Q] / sig;  // u2[t] / sigma2[t]
            }
            A = An; B = Bn;
        }
        if (j == 0) {
            atomicAdd(&pacc[0], sumlog);
            atomicAdd(&pacc[1], sumratio);
        }
    }
}

// --- K4: assemble scalar NLL ---------------------------------------------
extern "C" __global__ void k4_final(const float* __restrict__ wsf,
                                    float* __restrict__ out, int n) {
    if (threadIdx.x == 0 && blockIdx.x == 0) {
        double cst = 0.5 * (double)n * 1.8378770664093454;   // log(2*pi)
        out[0] = (float)(cst + 0.5 * (double)wsf[4] + 0.5 * (double)wsf[5]);
    }
}

extern "C" void kernel_launch(void* const* d_in, const int* in_sizes, int n_in,
                              void* d_out, int out_size, void* d_ws, size_t ws_size,
                              hipStream_t stream) {
    const float* r   = (const float*)d_in[0];
    const float* vol = (const float*)d_in[1];
    const float* a0  = (const float*)d_in[2];
    const float* a1  = (const float*)d_in[3];
    const float* rb0 = (const float*)d_in[4];
    const float* rb  = (const float*)d_in[5];
    const float* rw0 = (const float*)d_in[6];
    const float* rw  = (const float*)d_in[7];
    const float* rg  = (const float*)d_in[8];
    const float* rr  = (const float*)d_in[9];
    float* wsf = (float*)d_ws;
    float* out = (float*)d_out;
    const int T = in_sizes[0];
    const int n = T - 1;

    hipMemsetAsync(wsf, 0, 8 * sizeof(float), stream);   // zero accumulators
    hipLaunchKernelGGL(k1_stats, dim3(256), dim3(256), 0, stream,
                       r, a0, a1, wsf, n);
    hipLaunchKernelGGL(k2_params, dim3(1), dim3(256), 0, stream,
                       wsf, rb0, rb, rw0, rw, rg, rr, n);
    const int C = (n + LSTEP - 1) / LSTEP;
    hipLaunchKernelGGL(k3_main, dim3(C), dim3(256), 0, stream,
                       r, vol, a0, a1,
                       wsf + 128, wsf + 128 + KCH * Q,
                       wsf + 8, wsf + 40, wsf + 72,
                       wsf, wsf + 4, n);
    hipLaunchKernelGGL(k4_final, dim3(1), dim3(1), 0, stream, wsf, out, n);
}

// Round 2
// 207.970 us; speedup vs baseline: 1.5646x; 1.5646x over previous
//
#include <hip/hip_runtime.h>
#include <math.h>

#define KCH 32          // channels k
#define Q 64            // taps q

// ---- fused fallback params (round-1 kernel) ----
#define LSTEP 240
#define WARM 16
#define TT (LSTEP + WARM)
#define TILE_X (TT + Q)
#define SROW 36

// ---- split-path params ----
#define CB 256          // conv positions per block
#define LCH 112         // scan chunk length (new steps)
#define WSC 16          // scan warm-up steps
#define CPB 16          // chunks per scan block (1 wave, quad per chunk)

__device__ __forceinline__ float sp_softplus(float x) {
    return (x > 15.f) ? x : log1pf(expf(x));
}

// butterfly sum over lanes within each quad (lanes 0..3), via DPP quad_perm
__device__ __forceinline__ float quad_sum4(float v) {
    int vi = __float_as_int(v);
    int p1 = __builtin_amdgcn_update_dpp(0, vi, 0xB1, 0xF, 0xF, true); // xor 1
    v += __int_as_float(p1);
    vi = __float_as_int(v);
    int p2 = __builtin_amdgcn_update_dpp(0, vi, 0x4E, 0xF, 0xF, true); // xor 2
    v += __int_as_float(p2);
    return v;
}

// --- K1: sum(u2), sum(u2^2) ---------------------------------------------
extern "C" __global__ void k1_stats(const float* __restrict__ r,
                                    const float* __restrict__ a0p,
                                    const float* __restrict__ a1p,
                                    float* __restrict__ wsf, int n) {
    const float a0 = a0p[0], a1 = a1p[0];
    float s1 = 0.f, s2 = 0.f;
    for (int t = blockIdx.x * blockDim.x + threadIdx.x; t < n;
         t += gridDim.x * blockDim.x) {
        float u = r[t + 1] - a0 - a1 * r[t];
        float u2 = u * u;
        s1 += u2;
        s2 += u2 * u2;
    }
#pragma unroll
    for (int off = 32; off > 0; off >>= 1) {
        s1 += __shfl_down(s1, off);
        s2 += __shfl_down(s2, off);
    }
    __shared__ float b1[8], b2[8];
    int wid = threadIdx.x >> 6;
    if ((threadIdx.x & 63) == 0) { b1[wid] = s1; b2[wid] = s2; }
    __syncthreads();
    if (threadIdx.x == 0) {
        float t1 = 0.f, t2 = 0.f;
        int nw = blockDim.x >> 6;
        for (int i = 0; i < nw; i++) { t1 += b1[i]; t2 += b2[i]; }
        atomicAdd(&wsf[0], t1);
        atomicAdd(&wsf[1], t2);
    }
}

// --- K2: variance + softplus params into ws ------------------------------
// ws layout (floats): [0]=sum_u2 [1]=sum_u2sq [2]=var [3]=sigma2_init
// [4]=acc_sumlog [5]=acc_sumratio [6]=beta0 [8..40)=beta [40..72)=rho
// [72..104)=w0  [128..128+2048)=PW[m][i]  [2176..4224)=PG[m][i]
extern "C" __global__ void k2_params(float* __restrict__ wsf,
                                     const float* __restrict__ rb0,
                                     const float* __restrict__ rb,
                                     const float* __restrict__ rw0,
                                     const float* __restrict__ rw,
                                     const float* __restrict__ rg,
                                     const float* __restrict__ rr, int n) {
    int tid = threadIdx.x;
    if (tid == 0) {
        float s1 = wsf[0], s2 = wsf[1];
        float nf = (float)n;
        float mean = s1 / nf;
        float var = fmaxf((s2 - nf * mean * mean) / (nf - 1.f), 0.f);
        wsf[2] = var;
        wsf[3] = var + 1e-6f;
        wsf[6] = sp_softplus(rb0[0]);
    }
    if (tid < KCH) {
        wsf[8 + tid]  = sp_softplus(rb[tid]);
        wsf[40 + tid] = sp_softplus(rr[tid]);
        wsf[72 + tid] = sp_softplus(rw0[tid]);
    }
    for (int idx = tid; idx < KCH * Q; idx += blockDim.x) {
        int m = idx >> 5;       // tap index (already reversed)
        int i = idx & 31;       // channel
        wsf[128 + idx]           = sp_softplus(rw[i * Q + (Q - 1 - m)]);
        wsf[128 + KCH * Q + idx] = sp_softplus(rg[i * Q + (Q - 1 - m)]);
    }
}

// --- K3c (split): conv -> s[n][32], u2[n] --------------------------------
extern "C" __global__ void __launch_bounds__(256)
k3c_conv(const float* __restrict__ r, const float* __restrict__ vol,
         const float* __restrict__ a0p, const float* __restrict__ a1p,
         const float* __restrict__ pw, const float* __restrict__ pg,
         const float* __restrict__ pw0, const float* __restrict__ pscal,
         float* __restrict__ s_out, float* __restrict__ u2_out, int n) {
    __shared__ float Ul[CB + Q];
    __shared__ float Vl[CB + Q];
    const int t0 = blockIdx.x * CB;
    const float a0 = a0p[0], a1 = a1p[0];
    const float var = pscal[2];

    for (int idx = threadIdx.x; idx < CB + Q; idx += blockDim.x) {
        int x = t0 + idx;               // index into "full" (q + n) array space
        float uval, vval;
        if (x < Q) {
            uval = var;
            vval = vol[0];
        } else {
            int t = x - Q;
            uval = 0.f; vval = 0.f;
            if (t < n) {
                float u = r[t + 1] - a0 - a1 * r[t];
                uval = u * u;
                vval = vol[t];
            }
        }
        Ul[idx] = uval;
        Vl[idx] = vval;
    }
    __syncthreads();

    const int tloc = threadIdx.x;
    const int t = t0 + tloc;
    float acc[KCH];
#pragma unroll
    for (int i = 0; i < KCH; i++) acc[i] = pw0[i];
#pragma unroll 4
    for (int m = 0; m < Q; m++) {
        float uv = Ul[tloc + m];
        float vv = Vl[tloc + m];
        const float* __restrict__ wrow = pw + m * KCH;  // wave-uniform addr
        const float* __restrict__ grow = pg + m * KCH;
#pragma unroll
        for (int i = 0; i < KCH; i++)
            acc[i] = fmaf(uv, wrow[i], fmaf(vv, grow[i], acc[i]));
    }
    if (t < n) {
        u2_out[t] = Ul[tloc + Q];
        float* sp = s_out + (size_t)t * KCH;
#pragma unroll
        for (int g = 0; g < KCH / 4; g++) {
            float4 v4 = make_float4(acc[4 * g], acc[4 * g + 1],
                                    acc[4 * g + 2], acc[4 * g + 3]);
            *reinterpret_cast<float4*>(sp + 4 * g) = v4;
        }
    }
}

// --- K3s (split): chunked scan over s, 16 chunks per wave ----------------
extern "C" __global__ void __launch_bounds__(64)
k3s_scan(const float* __restrict__ s, const float* __restrict__ u2a,
         const float* __restrict__ pbeta, const float* __restrict__ prho,
         const float* __restrict__ pscal, float* __restrict__ pacc,
         int n, int C) {
    const int quad = threadIdx.x >> 2;
    const int laneq = threadIdx.x & 3;
    const int chunk = blockIdx.x * CPB + quad;

    float rho_c[8], beta_c[8];
#pragma unroll
    for (int e = 0; e < 8; e++) {
        rho_c[e]  = prho[laneq * 8 + e];
        beta_c[e] = pbeta[laneq * 8 + e];
    }
    const float bconst = pscal[6] + 1e-8f;   // beta0 + 1e-8
    float sig = pscal[3];                    // sigma2_init warm start
    float sumlog = 0.f, sumratio = 0.f;

    int base = 0, warm = 0, send = 0;
    if (chunk < C) {
        const int cstart = chunk * LCH;
        warm = (chunk == 0) ? 0 : WSC;
        base = cstart - warm;
        send = warm + min(LCH, n - cstart);
    }
    const int send4 = (send + 3) & ~3;
    const float* sbase = s + laneq * 8;

    float4 bA[4], bB[4];
    float bu[4];
#pragma unroll
    for (int d = 0; d < 4; d++) {
        int tt = (d < send) ? (base + d) : 0;
        const float* p = sbase + (size_t)tt * KCH;
        bA[d] = *reinterpret_cast<const float4*>(p);
        bB[d] = *reinterpret_cast<const float4*>(p + 4);
        bu[d] = u2a[tt];
    }

#define SCAN_STEP(d)                                                          \
    {                                                                         \
        const int s2 = s0 + (d);                                              \
        float4 A = bA[d]; float4 B = bB[d]; float uu = bu[d];                 \
        int tn = base + s2 + 4; tn = (tn < n) ? tn : (n - 1);                 \
        if (tn < 0) tn = 0;                                                   \
        const float* pf = sbase + (size_t)tn * KCH;                           \
        bA[d] = *reinterpret_cast<const float4*>(pf);                         \
        bB[d] = *reinterpret_cast<const float4*>(pf + 4);                     \
        bu[d] = u2a[tn];                                                      \
        float h0 = fmaxf(fmaf(rho_c[0], sig, A.x), 0.f);                      \
        float h1 = fmaxf(fmaf(rho_c[1], sig, A.y), 0.f);                      \
        float h2 = fmaxf(fmaf(rho_c[2], sig, A.z), 0.f);                      \
        float h3 = fmaxf(fmaf(rho_c[3], sig, A.w), 0.f);                      \
        float h4 = fmaxf(fmaf(rho_c[4], sig, B.x), 0.f);                      \
        float h5 = fmaxf(fmaf(rho_c[5], sig, B.y), 0.f);                      \
        float h6 = fmaxf(fmaf(rho_c[6], sig, B.z), 0.f);                      \
        float h7 = fmaxf(fmaf(rho_c[7], sig, B.w), 0.f);                      \
        float p0 = beta_c[0] * h0;                                            \
        float p1 = beta_c[1] * h1;                                            \
        p0 = fmaf(beta_c[2], h2, p0);                                         \
        p1 = fmaf(beta_c[3], h3, p1);                                         \
        p0 = fmaf(beta_c[4], h4, p0);                                         \
        p1 = fmaf(beta_c[5], h5, p1);                                         \
        p0 = fmaf(beta_c[6], h6, p0);                                         \
        p1 = fmaf(beta_c[7], h7, p1);                                         \
        float dsum = quad_sum4(p0 + p1);                                      \
        sig = bconst + dsum;                                                  \
        float logv = __logf(sig);                                             \
        float rat = uu * __builtin_amdgcn_rcpf(sig);                          \
        bool live = (s2 >= warm) && (s2 < send);                              \
        sumlog += live ? logv : 0.f;                                          \
        sumratio += live ? rat : 0.f;                                         \
    }

    for (int s0 = 0; s0 < send4; s0 += 4) {
        SCAN_STEP(0)
        SCAN_STEP(1)
        SCAN_STEP(2)
        SCAN_STEP(3)
    }
#undef SCAN_STEP

    if (laneq != 0) { sumlog = 0.f; sumratio = 0.f; }
#pragma unroll
    for (int off = 32; off > 0; off >>= 1) {
        sumlog += __shfl_down(sumlog, off);
        sumratio += __shfl_down(sumratio, off);
    }
    if (threadIdx.x == 0) {
        atomicAdd(&pacc[0], sumlog);
        atomicAdd(&pacc[1], sumratio);
    }
}

// --- K3 fused fallback (round-1 kernel, used if ws too small) ------------
extern "C" __global__ void __launch_bounds__(256, 4)
k3_fused(const float* __restrict__ r, const float* __restrict__ vol,
         const float* __restrict__ a0p, const float* __restrict__ a1p,
         const float* __restrict__ pw, const float* __restrict__ pg,
         const float* __restrict__ pbeta, const float* __restrict__ prho,
         const float* __restrict__ pw0, const float* __restrict__ pscal,
         float* __restrict__ pacc, int n) {
    __shared__ float Ul[TILE_X];
    __shared__ float Vl[TILE_X];
    __shared__ float Sl[TT + 1][SROW];

    const int c = blockIdx.x;
    const int tg0 = (c == 0) ? 0 : c * LSTEP - WARM;
    const int warm = (c == 0) ? 0 : WARM;
    const float a0 = a0p[0], a1 = a1p[0];
    const float var = pscal[2];

    for (int idx = threadIdx.x; idx < TILE_X; idx += blockDim.x) {
        int x = tg0 + idx;
        float uval, vval;
        if (x < Q) {
            uval = var;
            vval = vol[0];
        } else {
            int t = x - Q;
            uval = 0.f; vval = 0.f;
            if (t < n) {
                float u = r[t + 1] - a0 - a1 * r[t];
                uval = u * u;
                vval = vol[t];
            }
        }
        Ul[idx] = uval;
        Vl[idx] = vval;
    }
    __syncthreads();

    {
        const int tloc = threadIdx.x;
        float acc[KCH];
#pragma unroll
        for (int i = 0; i < KCH; i++) acc[i] = pw0[i];
#pragma unroll 4
        for (int m = 0; m < Q; m++) {
            float uv = Ul[tloc + m];
            float vv = Vl[tloc + m];
            const float* __restrict__ wrow = pw + m * KCH;
            const float* __restrict__ grow = pg + m * KCH;
#pragma unroll
            for (int i = 0; i < KCH; i++)
                acc[i] = fmaf(uv, wrow[i], fmaf(vv, grow[i], acc[i]));
        }
#pragma unroll
        for (int g = 0; g < KCH / 4; g++) {
            float4 v4 = make_float4(acc[4 * g], acc[4 * g + 1],
                                    acc[4 * g + 2], acc[4 * g + 3]);
            *reinterpret_cast<float4*>(&Sl[tloc][4 * g]) = v4;
        }
    }
    __syncthreads();

    if (threadIdx.x < 4) {
        const int j = threadIdx.x;
        float rho_c[8], beta_c[8];
#pragma unroll
        for (int e = 0; e < 8; e++) {
            rho_c[e]  = prho[j * 8 + e];
            beta_c[e] = pbeta[j * 8 + e];
        }
        const float beta0 = pscal[6];
        float sig = pscal[3];
        const int send = min(warm + LSTEP, n - tg0);
        float sumlog = 0.f, sumratio = 0.f;

        float4 A = *reinterpret_cast<const float4*>(&Sl[0][j * 8]);
        float4 B = *reinterpret_cast<const float4*>(&Sl[0][j * 8 + 4]);
        for (int s2 = 0; s2 < send; s2++) {
            float4 An = *reinterpret_cast<const float4*>(&Sl[s2 + 1][j * 8]);
            float4 Bn = *reinterpret_cast<const float4*>(&Sl[s2 + 1][j * 8 + 4]);
            float h0 = fmaxf(fmaf(rho_c[0], sig, A.x), 0.f) * beta_c[0];
            float h1 = fmaxf(fmaf(rho_c[1], sig, A.y), 0.f) * beta_c[1];
            float h2 = fmaxf(fmaf(rho_c[2], sig, A.z), 0.f) * beta_c[2];
            float h3 = fmaxf(fmaf(rho_c[3], sig, A.w), 0.f) * beta_c[3];
            float h4 = fmaxf(fmaf(rho_c[4], sig, B.x), 0.f) * beta_c[4];
            float h5 = fmaxf(fmaf(rho_c[5], sig, B.y), 0.f) * beta_c[5];
            float h6 = fmaxf(fmaf(rho_c[6], sig, B.z), 0.f) * beta_c[6];
            float h7 = fmaxf(fmaf(rho_c[7], sig, B.w), 0.f) * beta_c[7];
            float d = ((h0 + h1) + (h2 + h3)) + ((h4 + h5) + (h6 + h7));
            d = quad_sum4(d);
            sig = beta0 + d + 1e-8f;
            if (s2 >= warm) {
                sumlog += __logf(sig);
                sumratio += Ul[s2 + Q] / sig;
            }
            A = An; B = Bn;
        }
        if (j == 0) {
            atomicAdd(&pacc[0], sumlog);
            atomicAdd(&pacc[1], sumratio);
        }
    }
}

// --- K4: assemble scalar NLL ---------------------------------------------
extern "C" __global__ void k4_final(const float* __restrict__ wsf,
                                    float* __restrict__ out, int n) {
    if (threadIdx.x == 0 && blockIdx.x == 0) {
        double cst = 0.5 * (double)n * 1.8378770664093454;   // log(2*pi)
        out[0] = (float)(cst + 0.5 * (double)wsf[4] + 0.5 * (double)wsf[5]);
    }
}

extern "C" void kernel_launch(void* const* d_in, const int* in_sizes, int n_in,
                              void* d_out, int out_size, void* d_ws, size_t ws_size,
                              hipStream_t stream) {
    const float* r   = (const float*)d_in[0];
    const float* vol = (const float*)d_in[1];
    const float* a0  = (const float*)d_in[2];
    const float* a1  = (const float*)d_in[3];
    const float* rb0 = (const float*)d_in[4];
    const float* rb  = (const float*)d_in[5];
    const float* rw0 = (const float*)d_in[6];
    const float* rw  = (const float*)d_in[7];
    const float* rg  = (const float*)d_in[8];
    const float* rr  = (const float*)d_in[9];
    float* wsf = (float*)d_ws;
    float* out = (float*)d_out;
    const int T = in_sizes[0];
    const int n = T - 1;

    // ws layout: params in [0, 4352) floats; u2[n] at u2_off; s[n][32] at s_off
    const size_t u2_off = 4352;
    const size_t s_off  = u2_off + (size_t)((n + 255) & ~255);
    const size_t need   = (s_off + (size_t)n * KCH) * sizeof(float);

    hipMemsetAsync(wsf, 0, 8 * sizeof(float), stream);
    hipLaunchKernelGGL(k1_stats, dim3(256), dim3(256), 0, stream,
                       r, a0, a1, wsf, n);
    hipLaunchKernelGGL(k2_params, dim3(1), dim3(256), 0, stream,
                       wsf, rb0, rb, rw0, rw, rg, rr, n);

    if (ws_size >= need) {
        float* u2a = wsf + u2_off;
        float* sarr = wsf + s_off;
        const int nb_conv = (n + CB - 1) / CB;
        hipLaunchKernelGGL(k3c_conv, dim3(nb_conv), dim3(256), 0, stream,
                           r, vol, a0, a1,
                           wsf + 128, wsf + 128 + KCH * Q,
                           wsf + 72, wsf, sarr, u2a, n);
        const int C = (n + LCH - 1) / LCH;
        const int nb_scan = (C + CPB - 1) / CPB;
        hipLaunchKernelGGL(k3s_scan, dim3(nb_scan), dim3(64), 0, stream,
                           sarr, u2a, wsf + 8, wsf + 40, wsf, wsf + 4, n, C);
    } else {
        const int Cf = (n + LSTEP - 1) / LSTEP;
        hipLaunchKernelGGL(k3_fused, dim3(Cf), dim3(256), 0, stream,
                           r, vol, a0, a1,
                           wsf + 128, wsf + 128 + KCH * Q,
                           wsf + 8, wsf + 40, wsf + 72,
                           wsf, wsf + 4, n);
    }
    hipLaunchKernelGGL(k4_final, dim3(1), dim3(1), 0, stream, wsf, out, n);
}

// Round 4
// 164.797 us; speedup vs baseline: 1.9744x; 1.2620x over previous
//
#include <hip/hip_runtime.h>
#include <math.h>

#define KCH 32          // channels k
#define Q 64            // taps q

// ---- MFMA conv params ----
#define TB 256          // timesteps per conv block
#define TILE (TB + Q)   // staged entries (320)
#define USTR 352        // LDS array stride (ushorts)

// ---- scan params ----
#define LCH 28          // scan chunk length (new steps)
#define WSC 12          // scan warm-up steps (contraction ~0.011/step)
#define CPB 16          // chunks per 64-thread scan block (quad per chunk)

// ---- fused fallback params (round-1 kernel) ----
#define LSTEP 240
#define WARM 16
#define TT (LSTEP + WARM)
#define TILE_X (TT + Q)
#define SROW 36

typedef __attribute__((ext_vector_type(8))) short short8;
typedef __attribute__((ext_vector_type(4))) float float4v;

__device__ __forceinline__ float sp_softplus(float x) {
    return (x > 15.f) ? x : log1pf(expf(x));
}

__device__ __forceinline__ unsigned short f2bf(float f) {
    union { float f; unsigned int u; } v; v.f = f;
    unsigned int u = v.u;
    unsigned int r = (u + 0x7FFFu + ((u >> 16) & 1u)) >> 16;   // RNE
    return (unsigned short)r;
}

// butterfly sum over lanes within each quad (lanes 0..3), via DPP quad_perm
__device__ __forceinline__ float quad_sum4(float v) {
    int vi = __float_as_int(v);
    int p1 = __builtin_amdgcn_update_dpp(0, vi, 0xB1, 0xF, 0xF, true); // xor 1
    v += __int_as_float(p1);
    vi = __float_as_int(v);
    int p2 = __builtin_amdgcn_update_dpp(0, vi, 0x4E, 0xF, 0xF, true); // xor 2
    v += __int_as_float(p2);
    return v;
}

// ws layout (floats):
// [0]=sum_u2 [1]=sum_u2sq [2]=var [3]=sigma2_init [4]=acc_sumlog
// [5]=acc_sumratio [6]=beta0 [7]=counter_k1(int) [8..40)=beta [40..72)=rho
// [72..104)=w0 [104]=counter_scan(int)
// [128..4224)  : fp32 PW[m][i], PG[m][i] (fallback path; 4096 floats)
// [4352..6400) : bf16 Wc[128][32] as ushort (4096 ush = 2048 float slots)
// [6656..)     : u2[n] fp32 ; then s[n][32] fp32
// NOTE round-3 bug: bf16 block at 2304 overlapped the fp32 copy [128,4224).
#define WOFF_FP32W 128
#define WOFF_BF16W 4352
#define WOFF_U2    6656

// --- K12: stats + (last block) param preprocessing -----------------------
extern "C" __global__ void k12_stats(const float* __restrict__ r,
                                     const float* __restrict__ a0p,
                                     const float* __restrict__ a1p,
                                     const float* __restrict__ rb0,
                                     const float* __restrict__ rb,
                                     const float* __restrict__ rw0,
                                     const float* __restrict__ rw,
                                     const float* __restrict__ rg,
                                     const float* __restrict__ rr,
                                     float* __restrict__ wsf,
                                     int n, int nblocks) {
    const float a0 = a0p[0], a1 = a1p[0];
    float s1 = 0.f, s2 = 0.f;
    for (int t = blockIdx.x * blockDim.x + threadIdx.x; t < n;
         t += gridDim.x * blockDim.x) {
        float u = r[t + 1] - a0 - a1 * r[t];
        float u2 = u * u;
        s1 += u2;
        s2 += u2 * u2;
    }
#pragma unroll
    for (int off = 32; off > 0; off >>= 1) {
        s1 += __shfl_down(s1, off);
        s2 += __shfl_down(s2, off);
    }
    __shared__ float b1[4], b2[4];
    __shared__ int lastflag;
    int wid = threadIdx.x >> 6;
    if ((threadIdx.x & 63) == 0) { b1[wid] = s1; b2[wid] = s2; }
    __syncthreads();
    if (threadIdx.x == 0) {
        float t1 = b1[0] + b1[1] + b1[2] + b1[3];
        float t2 = b2[0] + b2[1] + b2[2] + b2[3];
        atomicAdd(&wsf[0], t1);
        atomicAdd(&wsf[1], t2);
        __threadfence();
        int old = atomicAdd((int*)(wsf + 7), 1);
        lastflag = (old == nblocks - 1) ? 1 : 0;
    }
    __syncthreads();
    if (!lastflag) return;

    // ---- last block: k2 work ----
    const int tid = threadIdx.x;
    if (tid == 0) {
        float t1 = atomicAdd(&wsf[0], 0.f);
        float t2 = atomicAdd(&wsf[1], 0.f);
        float nf = (float)n;
        float mean = t1 / nf;
        float var = fmaxf((t2 - nf * mean * mean) / (nf - 1.f), 0.f);
        wsf[2] = var;
        wsf[3] = var + 1e-6f;
        wsf[6] = sp_softplus(rb0[0]);
    }
    if (tid < KCH) {
        wsf[8 + tid]  = sp_softplus(rb[tid]);
        wsf[40 + tid] = sp_softplus(rr[tid]);
        wsf[72 + tid] = sp_softplus(rw0[tid]);
    }
    unsigned short* Wb = (unsigned short*)(wsf + WOFF_BF16W);
    for (int idx = tid; idx < 2 * KCH * Q; idx += blockDim.x) {
        int k = idx >> 5;        // 0..127
        int i = idx & 31;        // channel
        float raw = (k < Q) ? rw[i * Q + (Q - 1 - k)]
                            : rg[i * Q + (Q - 1 - (k - Q))];
        float spv = sp_softplus(raw);
        Wb[idx] = f2bf(spv);
        wsf[WOFF_FP32W + idx] = spv;    // fp32 copy for fallback path
    }
}

// --- K3m: MFMA conv -> s[n][32], u2[n] -----------------------------------
extern "C" __global__ void __launch_bounds__(256)
k3c_mfma(const float* __restrict__ r, const float* __restrict__ vol,
         const float* __restrict__ a0p, const float* __restrict__ a1p,
         const float* __restrict__ wsf,
         float* __restrict__ s_out, float* __restrict__ u2_out, int n) {
    __shared__ unsigned short UV[4 * USTR];
    unsigned short* Ue = UV;
    unsigned short* Uo = UV + USTR;
    unsigned short* Ve = UV + 2 * USTR;
    unsigned short* Vo = UV + 3 * USTR;

    const int t0 = blockIdx.x * TB;
    const float a0 = a0p[0], a1 = a1p[0];
    const float var = wsf[2];

    for (int x = threadIdx.x; x < TILE; x += 256) {
        int f = t0 + x;                 // index into "full" (q + n) space
        float uval, vval;
        if (f < Q) {
            uval = var;
            vval = vol[0];
        } else {
            int t = f - Q;
            uval = 0.f; vval = 0.f;
            if (t < n) {
                float u = r[t + 1] - a0 - a1 * r[t];
                uval = u * u;
                vval = vol[t];
                u2_out[t] = uval;       // covers exactly [t0-64, t0+256)
            }
        }
        unsigned short ub = f2bf(uval), vb = f2bf(vval);
        Ue[x] = ub; Ve[x] = vb;
        if (x > 0) { Uo[x - 1] = ub; Vo[x - 1] = vb; }
    }
    __syncthreads();

    const int tid = threadIdx.x;
    const int lane = tid & 63;
    const int ln = lane & 15;            // MFMA row (A) / col (C,D) / col (B)
    const int q4 = (lane >> 4) & 3;
    const int q8 = q4 * 8;
    const int wv = tid >> 6;

    // B-fragments: Wc[128][32], lane holds B[c*32 + q8 + j][h*16 + ln]
    const unsigned short* Wb = (const unsigned short*)(wsf + WOFF_BF16W);
    short8 bf[4][2];
#pragma unroll
    for (int c = 0; c < 4; c++)
#pragma unroll
        for (int h = 0; h < 2; h++)
#pragma unroll
            for (int j = 0; j < 8; j++)
                bf[c][h][j] = (short)Wb[(c * 32 + q8 + j) * 32 + h * 16 + ln];
    const float w00 = wsf[72 + ln];
    const float w01 = wsf[72 + 16 + ln];

    const unsigned int* pUe = (const unsigned int*)Ue;
    const unsigned int* pUo = (const unsigned int*)Uo;
    const unsigned int* pVe = (const unsigned int*)Ve;
    const unsigned int* pVo = (const unsigned int*)Vo;

#pragma unroll
    for (int wt = 0; wt < 4; wt++) {
        const int st = wv * 64 + wt * 16;
        float4v acc0 = {0.f, 0.f, 0.f, 0.f};
        float4v acc1 = {0.f, 0.f, 0.f, 0.f};
#pragma unroll
        for (int c = 0; c < 4; c++) {
            int e0 = st + ln + (c & 1) * 32 + q8;   // first of 8 elements
            const unsigned int* pe = (c < 2) ? pUe : pVe;
            const unsigned int* po = (c < 2) ? pUo : pVo;
            const unsigned int* p = (e0 & 1) ? po : pe;
            int hx = e0 >> 1;                        // dword index, aligned
            union { unsigned int w[4]; short8 s; } A;
            A.w[0] = p[hx];
            A.w[1] = p[hx + 1];
            A.w[2] = p[hx + 2];
            A.w[3] = p[hx + 3];
            acc0 = __builtin_amdgcn_mfma_f32_16x16x32_bf16(A.s, bf[c][0], acc0, 0, 0, 0);
            acc1 = __builtin_amdgcn_mfma_f32_16x16x32_bf16(A.s, bf[c][1], acc1, 0, 0, 0);
        }
        const int rowb = t0 + st + q4 * 4;           // C/D: row=(lane>>4)*4+reg
#pragma unroll
        for (int rg_ = 0; rg_ < 4; rg_++) {
            int t = rowb + rg_;
            if (t < n) {
                s_out[(size_t)t * KCH + ln]      = acc0[rg_] + w00;
                s_out[(size_t)t * KCH + 16 + ln] = acc1[rg_] + w01;
            }
        }
    }
}

// --- K3s: chunked scan + (last block) final NLL --------------------------
extern "C" __global__ void __launch_bounds__(64)
k3s_scan(const float* __restrict__ s, const float* __restrict__ u2a,
         const float* __restrict__ pbeta, const float* __restrict__ prho,
         const float* __restrict__ pscal, float* __restrict__ pacc,
         float* __restrict__ out, int n, int C, int nblocks) {
    const int quad = threadIdx.x >> 2;
    const int laneq = threadIdx.x & 3;
    const int chunk = blockIdx.x * CPB + quad;

    float rho_c[8], beta_c[8];
#pragma unroll
    for (int e = 0; e < 8; e++) {
        rho_c[e]  = prho[laneq * 8 + e];
        beta_c[e] = pbeta[laneq * 8 + e];
    }
    const float bconst = pscal[6] + 1e-8f;   // beta0 + 1e-8
    float sig = pscal[3];                    // sigma2_init warm start
    float sumlog = 0.f, sumratio = 0.f;

    int base = 0, warm = 0, send = 0;
    if (chunk < C) {
        const int cstart = chunk * LCH;
        warm = (chunk == 0) ? 0 : WSC;
        base = cstart - warm;
        send = warm + min(LCH, n - cstart);
    }
    const int send4 = (send + 3) & ~3;
    const float* sbase = s + laneq * 8;

    float4 bA[4], bB[4];
    float bu[4];
#pragma unroll
    for (int d = 0; d < 4; d++) {
        int tt = (d < send) ? (base + d) : 0;
        const float* p = sbase + (size_t)tt * KCH;
        bA[d] = *reinterpret_cast<const float4*>(p);
        bB[d] = *reinterpret_cast<const float4*>(p + 4);
        bu[d] = u2a[tt];
    }

#define SCAN_STEP(d)                                                          \
    {                                                                         \
        const int s2 = s0 + (d);                                              \
        float4 A = bA[d]; float4 B = bB[d]; float uu = bu[d];                 \
        int tn = base + s2 + 4; tn = (tn < n) ? tn : (n - 1);                 \
        const float* pf = sbase + (size_t)tn * KCH;                           \
        bA[d] = *reinterpret_cast<const float4*>(pf);                         \
        bB[d] = *reinterpret_cast<const float4*>(pf + 4);                     \
        bu[d] = u2a[tn];                                                      \
        float h0 = fmaxf(fmaf(rho_c[0], sig, A.x), 0.f);                      \
        float h1 = fmaxf(fmaf(rho_c[1], sig, A.y), 0.f);                      \
        float h2 = fmaxf(fmaf(rho_c[2], sig, A.z), 0.f);                      \
        float h3 = fmaxf(fmaf(rho_c[3], sig, A.w), 0.f);                      \
        float h4 = fmaxf(fmaf(rho_c[4], sig, B.x), 0.f);                      \
        float h5 = fmaxf(fmaf(rho_c[5], sig, B.y), 0.f);                      \
        float h6 = fmaxf(fmaf(rho_c[6], sig, B.z), 0.f);                      \
        float h7 = fmaxf(fmaf(rho_c[7], sig, B.w), 0.f);                      \
        float p0 = beta_c[0] * h0;                                            \
        float p1 = beta_c[1] * h1;                                            \
        p0 = fmaf(beta_c[2], h2, p0);                                         \
        p1 = fmaf(beta_c[3], h3, p1);                                         \
        p0 = fmaf(beta_c[4], h4, p0);                                         \
        p1 = fmaf(beta_c[5], h5, p1);                                         \
        p0 = fmaf(beta_c[6], h6, p0);                                         \
        p1 = fmaf(beta_c[7], h7, p1);                                         \
        float dsum = quad_sum4(p0 + p1);                                      \
        sig = bconst + dsum;                                                  \
        float logv = __logf(sig);                                             \
        float rat = uu * __builtin_amdgcn_rcpf(sig);                          \
        bool live = (s2 >= warm) && (s2 < send);                              \
        sumlog += live ? logv : 0.f;                                          \
        sumratio += live ? rat : 0.f;                                         \
    }

    for (int s0 = 0; s0 < send4; s0 += 4) {
        SCAN_STEP(0)
        SCAN_STEP(1)
        SCAN_STEP(2)
        SCAN_STEP(3)
    }
#undef SCAN_STEP

    if (laneq != 0) { sumlog = 0.f; sumratio = 0.f; }
#pragma unroll
    for (int off = 32; off > 0; off >>= 1) {
        sumlog += __shfl_down(sumlog, off);
        sumratio += __shfl_down(sumratio, off);
    }
    if (threadIdx.x == 0) {
        atomicAdd(&pacc[0], sumlog);
        atomicAdd(&pacc[1], sumratio);
        __threadfence();
        int old = atomicAdd((int*)(pscal + 104), 1);
        if (old == nblocks - 1) {
            float sl = atomicAdd(&pacc[0], 0.f);
            float sr = atomicAdd(&pacc[1], 0.f);
            double cst = 0.5 * (double)n * 1.8378770664093454;  // log(2*pi)
            out[0] = (float)(cst + 0.5 * (double)sl + 0.5 * (double)sr);
        }
    }
}

// --- fused fallback (round-1 kernel, used only if ws too small) ----------
extern "C" __global__ void __launch_bounds__(256, 4)
k3_fused(const float* __restrict__ r, const float* __restrict__ vol,
         const float* __restrict__ a0p, const float* __restrict__ a1p,
         const float* __restrict__ pw, const float* __restrict__ pg,
         const float* __restrict__ pbeta, const float* __restrict__ prho,
         const float* __restrict__ pw0, const float* __restrict__ pscal,
         float* __restrict__ pacc, int n) {
    __shared__ float Ul[TILE_X];
    __shared__ float Vl[TILE_X];
    __shared__ float Sl[TT + 1][SROW];

    const int c = blockIdx.x;
    const int tg0 = (c == 0) ? 0 : c * LSTEP - WARM;
    const int warm = (c == 0) ? 0 : WARM;
    const float a0 = a0p[0], a1 = a1p[0];
    const float var = pscal[2];

    for (int idx = threadIdx.x; idx < TILE_X; idx += blockDim.x) {
        int x = tg0 + idx;
        float uval, vval;
        if (x < Q) { uval = var; vval = vol[0]; }
        else {
            int t = x - Q;
            uval = 0.f; vval = 0.f;
            if (t < n) {
                float u = r[t + 1] - a0 - a1 * r[t];
                uval = u * u;
                vval = vol[t];
            }
        }
        Ul[idx] = uval;
        Vl[idx] = vval;
    }
    __syncthreads();
    {
        const int tloc = threadIdx.x;
        float acc[KCH];
#pragma unroll
        for (int i = 0; i < KCH; i++) acc[i] = pw0[i];
#pragma unroll 4
        for (int m = 0; m < Q; m++) {
            float uv = Ul[tloc + m];
            float vv = Vl[tloc + m];
            const float* __restrict__ wrow = pw + m * KCH;
            const float* __restrict__ grow = pg + m * KCH;
#pragma unroll
            for (int i = 0; i < KCH; i++)
                acc[i] = fmaf(uv, wrow[i], fmaf(vv, grow[i], acc[i]));
        }
#pragma unroll
        for (int g = 0; g < KCH / 4; g++) {
            float4 v4 = make_float4(acc[4 * g], acc[4 * g + 1],
                                    acc[4 * g + 2], acc[4 * g + 3]);
            *reinterpret_cast<float4*>(&Sl[tloc][4 * g]) = v4;
        }
    }
    __syncthreads();
    if (threadIdx.x < 4) {
        const int j = threadIdx.x;
        float rho_c[8], beta_c[8];
#pragma unroll
        for (int e = 0; e < 8; e++) {
            rho_c[e]  = prho[j * 8 + e];
            beta_c[e] = pbeta[j * 8 + e];
        }
        const float beta0 = pscal[6];
        float sig = pscal[3];
        const int send = min(warm + LSTEP, n - tg0);
        float sumlog = 0.f, sumratio = 0.f;
        float4 A = *reinterpret_cast<const float4*>(&Sl[0][j * 8]);
        float4 B = *reinterpret_cast<const float4*>(&Sl[0][j * 8 + 4]);
        for (int s2 = 0; s2 < send; s2++) {
            float4 An = *reinterpret_cast<const float4*>(&Sl[s2 + 1][j * 8]);
            float4 Bn = *reinterpret_cast<const float4*>(&Sl[s2 + 1][j * 8 + 4]);
            float h0 = fmaxf(fmaf(rho_c[0], sig, A.x), 0.f) * beta_c[0];
            float h1 = fmaxf(fmaf(rho_c[1], sig, A.y), 0.f) * beta_c[1];
            float h2 = fmaxf(fmaf(rho_c[2], sig, A.z), 0.f) * beta_c[2];
            float h3 = fmaxf(fmaf(rho_c[3], sig, A.w), 0.f) * beta_c[3];
            float h4 = fmaxf(fmaf(rho_c[4], sig, B.x), 0.f) * beta_c[4];
            float h5 = fmaxf(fmaf(rho_c[5], sig, B.y), 0.f) * beta_c[5];
            float h6 = fmaxf(fmaf(rho_c[6], sig, B.z), 0.f) * beta_c[6];
            float h7 = fmaxf(fmaf(rho_c[7], sig, B.w), 0.f) * beta_c[7];
            float d = ((h0 + h1) + (h2 + h3)) + ((h4 + h5) + (h6 + h7));
            d = quad_sum4(d);
            sig = beta0 + d + 1e-8f;
            if (s2 >= warm) {
                sumlog += __logf(sig);
                sumratio += Ul[s2 + Q] / sig;
            }
            A = An; B = Bn;
        }
        if (j == 0) {
            atomicAdd(&pacc[0], sumlog);
            atomicAdd(&pacc[1], sumratio);
        }
    }
}

extern "C" __global__ void k4_final(const float* __restrict__ wsf,
                                    float* __restrict__ out, int n) {
    if (threadIdx.x == 0 && blockIdx.x == 0) {
        double cst = 0.5 * (double)n * 1.8378770664093454;
        out[0] = (float)(cst + 0.5 * (double)wsf[4] + 0.5 * (double)wsf[5]);
    }
}

extern "C" void kernel_launch(void* const* d_in, const int* in_sizes, int n_in,
                              void* d_out, int out_size, void* d_ws, size_t ws_size,
                              hipStream_t stream) {
    const float* r   = (const float*)d_in[0];
    const float* vol = (const float*)d_in[1];
    const float* a0  = (const float*)d_in[2];
    const float* a1  = (const float*)d_in[3];
    const float* rb0 = (const float*)d_in[4];
    const float* rb  = (const float*)d_in[5];
    const float* rw0 = (const float*)d_in[6];
    const float* rw  = (const float*)d_in[7];
    const float* rg  = (const float*)d_in[8];
    const float* rr  = (const float*)d_in[9];
    float* wsf = (float*)d_ws;
    float* out = (float*)d_out;
    const int T = in_sizes[0];
    const int n = T - 1;

    const size_t u2_off = WOFF_U2;
    const size_t s_off  = u2_off + (size_t)((n + 255) & ~255);
    const size_t need   = (s_off + (size_t)n * KCH) * sizeof(float);

    hipMemsetAsync(wsf, 0, 512, stream);   // zero accumulators + counters
    hipLaunchKernelGGL(k12_stats, dim3(256), dim3(256), 0, stream,
                       r, a0, a1, rb0, rb, rw0, rw, rg, rr, wsf, n, 256);

    if (ws_size >= need) {
        float* u2a  = wsf + u2_off;
        float* sarr = wsf + s_off;
        const int nb_conv = (n + TB - 1) / TB;
        hipLaunchKernelGGL(k3c_mfma, dim3(nb_conv), dim3(256), 0, stream,
                           r, vol, a0, a1, wsf, sarr, u2a, n);
        const int C = (n + LCH - 1) / LCH;
        const int nb_scan = (C + CPB - 1) / CPB;
        hipLaunchKernelGGL(k3s_scan, dim3(nb_scan), dim3(64), 0, stream,
                           sarr, u2a, wsf + 8, wsf + 40, wsf, wsf + 4,
                           out, n, C, nb_scan);
    } else {
        const int Cf = (n + LSTEP - 1) / LSTEP;
        hipLaunchKernelGGL(k3_fused, dim3(Cf), dim3(256), 0, stream,
                           r, vol, a0, a1,
                           wsf + WOFF_FP32W, wsf + WOFF_FP32W + KCH * Q,
                           wsf + 8, wsf + 40, wsf + 72,
                           wsf, wsf + 4, n);
        hipLaunchKernelGGL(k4_final, dim3(1), dim3(1), 0, stream, wsf, out, n);
    }
}